// Round 3
// baseline (833.955 us; speedup 1.0000x reference)
//
#include <hip/hip_runtime.h>
#include <hip/hip_cooperative_groups.h>

namespace cg = cooperative_groups;

#define B_   64
#define N_   2304
#define D_   8
#define J_   32
#define L_   16
#define EPS_ 1e-7f
#define NPB  9        // n-rows per block
#define NBLK 256      // blocks (= n-chunks); NBLK*NPB == N_
#define NTHR 512      // threads per block (8 waves)

// dynamic LDS layout (floats):
//   Ws_lds [NPB][32][16]      4608   sum_k W for this block's n-rows
//   wgt    [NPB][64][32]     18432   logits -> wgt, j XOR-swizzled by (b&31)
//   xs     [NPB][64]           576   sum_i x for this block's n-rows
// total 23616 floats = 94464 bytes
#define LDS_FLOATS (NPB*512 + NPB*64*32 + NPB*64)

extern "C" __global__ void __launch_bounds__(NTHR, 2)
caps_kernel(const float* __restrict__ x, const float* __restrict__ W,
            float* __restrict__ out, float* __restrict__ u, float* __restrict__ p)
{
    cg::grid_group grid = cg::this_grid();
    extern __shared__ float smem[];
    float* Ws_lds  = smem;                    // [NPB][32][16]
    float* wgt_lds = smem + NPB * 512;        // [NPB][64][32]
    float* xs_lds  = wgt_lds + NPB * 64 * 32; // [NPB][64]

    const int tid  = threadIdx.x;
    const int wave = tid >> 6;
    const int lane = tid & 63;                // = b in phases A/B
    const int blk  = blockIdx.x;
    const int n0   = blk * NPB;
    const int jg   = wave * 4;                // this wave's j-group base

    // ---------- setup: Ws_lds = sum_k W rows, xs_lds = sum_i x ----------
    for (int o4 = tid; o4 < NPB * 128; o4 += NTHR) {
        const int nn = o4 >> 7;
        const int r  = o4 & 127;              // j*4 + l4
        const float4* base = (const float4*)W + (size_t)(n0 + nn) * 1024 + (r >> 2) * 32 + (r & 3);
        float4 s = make_float4(0.f, 0.f, 0.f, 0.f);
#pragma unroll
        for (int k = 0; k < D_; ++k) {
            float4 t = base[k * 4];
            s.x += t.x; s.y += t.y; s.z += t.z; s.w += t.w;
        }
        ((float4*)Ws_lds)[o4] = s;
    }
    for (int pp = tid; pp < 64 * NPB; pp += NTHR) {
        const int b  = pp / NPB;
        const int nn = pp - b * NPB;
        const float4* q4 = (const float4*)(x + ((size_t)b * N_ + n0 + nn) * D_);
        float4 a = q4[0], c = q4[1];
        xs_lds[nn * 64 + b] = a.x + a.y + a.z + a.w + c.x + c.y + c.z + c.w;
    }
    __syncthreads();

    for (int t = 0; t < 3; ++t) {
        if (t > 0) {
            // ---------- Phase A: logits for this wave's 4 j over all 9 n ----------
            // u read once per thread (its b, its 4 j): 16 float4 -> registers
            float4 ur[4][4];
#pragma unroll
            for (int q = 0; q < 4; ++q) {
                const float4* up = (const float4*)(u + ((size_t)(jg + q) * 64 + lane) * L_);
#pragma unroll
                for (int d = 0; d < 4; ++d) ur[q][d] = up[d];
            }
            float lg[NPB][4];
#pragma unroll
            for (int nn = 0; nn < NPB; ++nn) {
                const float xsv = xs_lds[nn * 64 + lane];
#pragma unroll
                for (int q = 0; q < 4; ++q) {
                    const float4* wp = (const float4*)(Ws_lds + nn * 512 + (jg + q) * 16);
                    float4 w0 = wp[0], w1 = wp[1], w2 = wp[2], w3 = wp[3];
                    float d =  w0.x * ur[q][0].x + w0.y * ur[q][0].y + w0.z * ur[q][0].z + w0.w * ur[q][0].w
                             + w1.x * ur[q][1].x + w1.y * ur[q][1].y + w1.z * ur[q][1].z + w1.w * ur[q][1].w
                             + w2.x * ur[q][2].x + w2.y * ur[q][2].y + w2.z * ur[q][2].z + w2.w * ur[q][2].w
                             + w3.x * ur[q][3].x + w3.y * ur[q][3].y + w3.z * ur[q][3].z + w3.w * ur[q][3].w;
                    lg[nn][q] = d * xsv;
                }
            }
            // write logits, j-slot XOR-swizzled by (b&31): bank = (j^b)&31 -> conflict-free
#pragma unroll
            for (int nn = 0; nn < NPB; ++nn)
#pragma unroll
                for (int q = 0; q < 4; ++q)
                    wgt_lds[(nn * 64 + lane) * 32 + ((jg + q) ^ (lane & 31))] = lg[nn][q];
            __syncthreads();

            // ---------- mini-softmax: one (n,b) row per thread ----------
            for (int pp = tid; pp < NPB * 64; pp += NTHR) {
                const int n_ = pp >> 6;
                const int b_ = pp & 63;
                const int bb = b_ & 31;
                float* row = wgt_lds + (n_ * 64 + b_) * 32;
                float r[32];
#pragma unroll
                for (int jj = 0; jj < 32; ++jj) r[jj] = row[jj ^ bb];
                float m = r[0];
#pragma unroll
                for (int jj = 1; jj < 32; ++jj) m = fmaxf(m, r[jj]);
                float ssum = 0.f;
#pragma unroll
                for (int jj = 0; jj < 32; ++jj) { r[jj] = __expf(r[jj] - m); ssum += r[jj]; }
                const float sc = xs_lds[n_ * 64 + b_] / ssum;   // wgt = c * xs
#pragma unroll
                for (int jj = 0; jj < 32; ++jj) row[jj ^ bb] = r[jj] * sc;
            }
            __syncthreads();
        }

        // ---------- Phase B: acc[j-local][l] += wgt * Ws ----------
        float acc[4][16];
#pragma unroll
        for (int q = 0; q < 4; ++q)
#pragma unroll
            for (int l = 0; l < 16; ++l) acc[q][l] = 0.f;

#pragma unroll
        for (int nn = 0; nn < NPB; ++nn) {
#pragma unroll
            for (int q = 0; q < 4; ++q) {
                const float w = (t == 0)
                    ? xs_lds[nn * 64 + lane] * (1.f / 32.f)
                    : wgt_lds[(nn * 64 + lane) * 32 + ((jg + q) ^ (lane & 31))];
                const float4* wp = (const float4*)(Ws_lds + nn * 512 + (jg + q) * 16);
#pragma unroll
                for (int d = 0; d < 4; ++d) {
                    float4 wv = wp[d];
                    acc[q][d * 4 + 0] += w * wv.x;
                    acc[q][d * 4 + 1] += w * wv.y;
                    acc[q][d * 4 + 2] += w * wv.z;
                    acc[q][d * 4 + 3] += w * wv.w;
                }
            }
        }
        // partials p[blk][j][b][l]
#pragma unroll
        for (int q = 0; q < 4; ++q) {
            float* pp = p + (size_t)blk * 32768 + (((jg + q) * 64) + lane) * 16;
#pragma unroll
            for (int d = 0; d < 4; ++d)
                ((float4*)pp)[d] = make_float4(acc[q][d * 4 + 0], acc[q][d * 4 + 1],
                                               acc[q][d * 4 + 2], acc[q][d * 4 + 3]);
        }
        __threadfence();
        grid.sync();

        // ---------- Phase C: reduce 256 chunks + squash ----------
        if (tid < 128) {
            const int g = blk * 128 + tid;          // g = j*1024 + b*16 + l
            float s = 0.f;
            for (int c = 0; c < NBLK; ++c) s += p[(size_t)c * 32768 + g];
            float sq = s * s;
#pragma unroll
            for (int off = 8; off >= 1; off >>= 1) sq += __shfl_xor(sq, off);
            const float scale = sq / (1.f + sq) / sqrtf(sq + EPS_);
            const float v = scale * s;
            if (t == 0)      u[g] = v;
            else if (t == 1) u[g] += v;
            else {
                const int j = g >> 10, b = (g >> 4) & 63, l = g & 15;
                out[((size_t)b * 32 + j) * 16 + l] = v;
            }
        }
        if (t < 2) { __threadfence(); grid.sync(); }
    }
}

extern "C" void kernel_launch(void* const* d_in, const int* in_sizes, int n_in,
                              void* d_out, int out_size, void* d_ws, size_t ws_size,
                              hipStream_t stream) {
    const float* x = (const float*)d_in[0];   // [B, N, D]
    const float* W = (const float*)d_in[1];   // [N, J, D, L]
    float* out = (float*)d_out;               // [B, J, L]

    float* ws = (float*)d_ws;
    float* u  = ws;                            // J*B*L   = 32768 floats
    float* p  = u + (size_t)J_ * B_ * L_;      // NBLK*J*B*L = 8388608 floats (33.5 MB)

    (void)hipFuncSetAttribute((const void*)caps_kernel,
                              hipFuncAttributeMaxDynamicSharedMemorySize,
                              LDS_FLOATS * 4);

    void* args[] = { (void*)&x, (void*)&W, (void*)&out, (void*)&u, (void*)&p };
    (void)hipLaunchCooperativeKernel((const void*)caps_kernel,
                                     dim3(NBLK), dim3(NTHR),
                                     args, LDS_FLOATS * 4, stream);
}